// Round 5
// baseline (260.661 us; speedup 1.0000x reference)
//
#include <hip/hip_runtime.h>

// LIF spike recurrence over T axis.
// x: [B=32, T=8, C=128, H=32, W=32] fp32, out: same shape (0/1 spikes).
// mem = mem*0.5 + x_t; spike = (mem > 1.0); mem = spike ? 0 : mem.
//
// DIAGNOSTIC ROUND: launch the identical kernel TWICE (idempotent — the
// second dispatch recomputes and overwrites the same spikes) so the kernel's
// own dispatch shows up in rocprof's top-5 with full counters. All prior
// rounds only showed harness fill kernels; kernel-time estimates were
// subtraction-based guesses.

#define TT 8
#define INNER4 (128 * 32 * 32 / 4)   // C*H*W in float4 units = 32768

typedef float v4f __attribute__((ext_vector_type(4)));

__global__ __launch_bounds__(256) void lif_kernel(
    const v4f* __restrict__ x, v4f* __restrict__ out) {
    int idx = blockIdx.x * blockDim.x + threadIdx.x;   // 0 .. B*INNER4-1
    int b = idx >> 15;          // idx / INNER4
    int i = idx & (INNER4 - 1); // idx % INNER4

    // Base offset (float4 units) for (b, t=0, i)
    int base = b * (TT * INNER4) + i;

    // Hoist all 8 loads (independent addresses, nontemporal)
    v4f xv[TT];
#pragma unroll
    for (int t = 0; t < TT; ++t)
        xv[t] = __builtin_nontemporal_load(x + base + t * INNER4);

    v4f mem = {0.f, 0.f, 0.f, 0.f};
#pragma unroll
    for (int t = 0; t < TT; ++t) {
        mem = mem * 0.5f + xv[t];

        v4f sp;
        sp.x = (mem.x > 1.0f) ? 1.0f : 0.0f;
        sp.y = (mem.y > 1.0f) ? 1.0f : 0.0f;
        sp.z = (mem.z > 1.0f) ? 1.0f : 0.0f;
        sp.w = (mem.w > 1.0f) ? 1.0f : 0.0f;

        mem.x = (mem.x > 1.0f) ? 0.0f : mem.x;
        mem.y = (mem.y > 1.0f) ? 0.0f : mem.y;
        mem.z = (mem.z > 1.0f) ? 0.0f : mem.z;
        mem.w = (mem.w > 1.0f) ? 0.0f : mem.w;

        __builtin_nontemporal_store(sp, out + base + t * INNER4);
    }
}

extern "C" void kernel_launch(void* const* d_in, const int* in_sizes, int n_in,
                              void* d_out, int out_size, void* d_ws, size_t ws_size,
                              hipStream_t stream) {
    const v4f* x = (const v4f*)d_in[0];
    v4f* out = (v4f*)d_out;

    const int total4 = 32 * INNER4;   // 1,048,576 float4 work items
    const int block = 256;
    const int grid = total4 / block;  // 4096

    // Twice: identical, idempotent. Second dispatch exists purely so the
    // kernel's counters appear in the profile top-5.
    lif_kernel<<<grid, block, 0, stream>>>(x, out);
    lif_kernel<<<grid, block, 0, stream>>>(x, out);
}

// Round 6
// 217.572 us; speedup vs baseline: 1.1980x; 1.1980x over previous
//
#include <hip/hip_runtime.h>

// LIF spike recurrence over T axis.
// x: [B=32, T=8, C=128, H=32, W=32] fp32, out: same shape (0/1 spikes).
// mem = mem*0.5 + x_t; spike = (mem > 1.0); mem = spike ? 0 : mem.
//
// ROOFLINE-VERIFIED (round 5 diagnostic): one kernel pass measured at ~43 us
// via double-dispatch delta = 268 MB / 43 us = ~6.2 TB/s = ~98% of the
// achievable 6.3 TB/s HBM ceiling. Every element is read and written exactly
// once; the T-recurrence is register-resident. No further headroom without
// changing the I/O contract (fp32 in / fp32 out).
//
// Structure: one thread = one float4 (4 contiguous W elements) of one neuron,
// 8 independent NT loads hoisted -> full recurrence in regs -> NT stores.

#define TT 8
#define INNER4 (128 * 32 * 32 / 4)   // C*H*W in float4 units = 32768

typedef float v4f __attribute__((ext_vector_type(4)));

__global__ __launch_bounds__(256) void lif_kernel(
    const v4f* __restrict__ x, v4f* __restrict__ out) {
    int idx = blockIdx.x * blockDim.x + threadIdx.x;   // 0 .. B*INNER4-1
    int b = idx >> 15;          // idx / INNER4
    int i = idx & (INNER4 - 1); // idx % INNER4

    // Base offset (float4 units) for (b, t=0, i)
    int base = b * (TT * INNER4) + i;

    // Hoist all 8 loads (independent addresses, nontemporal)
    v4f xv[TT];
#pragma unroll
    for (int t = 0; t < TT; ++t)
        xv[t] = __builtin_nontemporal_load(x + base + t * INNER4);

    v4f mem = {0.f, 0.f, 0.f, 0.f};
#pragma unroll
    for (int t = 0; t < TT; ++t) {
        mem = mem * 0.5f + xv[t];

        v4f sp;
        sp.x = (mem.x > 1.0f) ? 1.0f : 0.0f;
        sp.y = (mem.y > 1.0f) ? 1.0f : 0.0f;
        sp.z = (mem.z > 1.0f) ? 1.0f : 0.0f;
        sp.w = (mem.w > 1.0f) ? 1.0f : 0.0f;

        mem.x = (mem.x > 1.0f) ? 0.0f : mem.x;
        mem.y = (mem.y > 1.0f) ? 0.0f : mem.y;
        mem.z = (mem.z > 1.0f) ? 0.0f : mem.z;
        mem.w = (mem.w > 1.0f) ? 0.0f : mem.w;

        __builtin_nontemporal_store(sp, out + base + t * INNER4);
    }
}

extern "C" void kernel_launch(void* const* d_in, const int* in_sizes, int n_in,
                              void* d_out, int out_size, void* d_ws, size_t ws_size,
                              hipStream_t stream) {
    const v4f* x = (const v4f*)d_in[0];
    v4f* out = (v4f*)d_out;

    const int total4 = 32 * INNER4;   // 1,048,576 float4 work items
    const int block = 256;
    const int grid = total4 / block;  // 4096
    lif_kernel<<<grid, block, 0, stream>>>(x, out);
}